// Round 9
// baseline (196.945 us; speedup 1.0000x reference)
//
#include <hip/hip_runtime.h>

// out = conv2d(poly(img), W, stride=1, pad=1) / 27, poly(v) = A0 + A1*v + A2*v^2
// (identity-kernel branch contributes exactly zero; 1/27 folded into poly).
// Implicit GEMM on bf16 MFMA: A = weights (M=o), B = poly(img) (N = spatial x),
// K = (ky,kx,c) = 576, mfma_f32_32x32x16_bf16.
//
// R13: in-order-vmcnt fix. All prior rounds had global weight loads (or DMA)
// inside/behind the MFMA phase; since vmcnt retires IN ORDER, the compiler's
// wait for an L1-hot weight also drained every older in-flight stage load ->
// prefetch overlap was silently zero every chunk (the universal 44 µs plateau,
// HBM duty ~40%). This round:
//  - ZERO vmem in the MFMA phase: weights per-chunk in LDS via global_load_lds
//    (slab padded to 24 KB -> exactly 3 loads/wave, uniform), B reg-staged.
//  - Wave-uniform load counts (16 stage loads/wave/chunk, dummy-padded and
//    clamped to an L1-hot address) + raw s_barrier + counted vmcnt(16):
//    stage loads for chunk k+2 stay in flight across the barrier AND all of
//    MFMA(k+1), retiring at the next pack. Queue invariant per wave:
//    [s16] -> +w3 -> pack(vmcnt(3) by compiler) -> +s16 -> vmcnt(16) -> [s16].
//  - 2-y-row blocks (acc[2][1] = 32 AGPR) so the 32-reg v-buffer fits under
//    the 128-reg tier: 512 thr, 8 waves = 2y x 4 x-tiles, 2 blocks/CU.
//  - LDS static 57,856 B (stag 2x16,640 + wlds 24,576). XCD swizzle kept
//    (R12: FETCH 49->34 MB). T5 setprio around the MFMA cluster.

typedef __bf16 bf16;
typedef __attribute__((ext_vector_type(8))) __bf16 bf16x8;
typedef __attribute__((ext_vector_type(16))) float f32x16;

static constexpr float A0 = -0.000287f / 27.0f;
static constexpr float A1 =  0.266f    / 27.0f;
static constexpr float A2 = -0.1097f   / 27.0f;

#define NN 16
#define CI 64
#define HH 128
#define WW 128
#define OO 64

// Repack weights [O][C][3][3] fp32 -> [chunk 4][pad 12288]: per-chunk slab
// [slice 9][ccl 2][o 64][cj 8] bf16 (9216 real + 3072 zero pad = 24 KB DMA units).
__global__ void repack_w(const float* __restrict__ w, bf16* __restrict__ wrb) {
    int idx = blockIdx.x * 256 + threadIdx.x;        // 4*12288 = 49152
    if (idx >= 49152) return;
    int chunk = idx / 12288;
    int e     = idx - chunk * 12288;
    if (e >= 9216) { wrb[idx] = (bf16)0.0f; return; }   // pad: deterministic, never read
    int cj = e & 7;
    int o  = (e >> 3) & 63;
    int sc = e >> 9;                 // slice*2 + ccl, 0..17
    int slice = sc >> 1, ccl = sc & 1;
    int c  = chunk * 16 + ccl * 8 + cj;
    int ky = slice / 3, kx = slice - ky * 3;
    wrb[idx] = (bf16)w[((o * CI + c) * 3 + ky) * 3 + kx];
}

__global__ __launch_bounds__(512, 4) void conv_mfma(const float* __restrict__ img,
                                                    const bf16* __restrict__ wrb,
                                                    float* __restrict__ out) {
    // stag[2]: [row 8 = r*2+ccl][xp 130][cj 8] bf16 = 16640 B each
    // wlds:    [slice 9][ccl 2][o 64][cj 8] bf16 + pad = 24576 B (current chunk)
    __shared__ __align__(16) bf16 stag[2][8320];
    __shared__ __align__(16) bf16 wlds[12288];

    const int tid  = threadIdx.x;
    const int braw = blockIdx.x;
    const int b    = (braw & 7) * 128 + (braw >> 3);   // XCD swizzle, bijective (1024%8==0)
    const int y0   = (b & 63) * 2;
    const int n    = b >> 6;

    const int wv   = tid >> 6;       // 0..7
    const int lane = tid & 63;
    const int lm   = lane & 31;      // A: o-row / B: x-col / C: col
    const int half = lane >> 5;      // k-half selector (ccl)
    const int yl   = wv >> 2;        // output row in tile (0..1)
    const int Xh   = (wv & 3) * 32;  // x sub-tile (0/32/64/96)

    // ---- B staging: 520 real items (r 4 x ccl 2 x xh 65), padded to 1024 so
    // EVERY thread issues exactly 16 float2 loads (2 rounds x 8) per chunk.
    // Dummy/halo/out-of-y items load a clamped L1-hot address and discard.
    auto sload = [&](int chunk, float2* v) {
        #pragma unroll
        for (int rd = 0; rd < 2; ++rd) {
            const int id  = tid + (rd << 9);
            const int r   = id / 130;
            const int rem = id - r * 130;
            const int ccl = rem / 65;
            const int xh  = rem - ccl * 65;
            const int yi  = y0 - 1 + r;
            const bool ok = (id < 520) && (xh < 64) && ((unsigned)yi < 128u);
            const float* p = ok ? img + ((n * CI + chunk * 16 + ccl * 8) * HH + yi) * WW + 2 * xh
                                : img;            // clamped dummy, L1-hot
            #pragma unroll
            for (int j = 0; j < 8; ++j)
                v[rd * 8 + j] = *(const float2*)(p + (ok ? j * HH * WW : 0));
        }
    };
    auto spack = [&](int buf, float2* v) {
        #pragma unroll
        for (int rd = 0; rd < 2; ++rd) {
            const int id = tid + (rd << 9);
            if (id >= 520) continue;
            const int r   = id / 130;
            const int rem = id - r * 130;
            const int ccl = rem / 65;
            const int xh  = rem - ccl * 65;
            const int yi  = y0 - 1 + r;
            bf16* rowp = &stag[buf][(r * 2 + ccl) * (130 * 8)];
            if (xh < 64) {
                bf16x8 pk0, pk1;
                if ((unsigned)yi < 128u) {
                    #pragma unroll
                    for (int j = 0; j < 8; ++j) {
                        const float a = v[rd * 8 + j].x, c = v[rd * 8 + j].y;
                        pk0[j] = (bf16)(A0 + a * (A1 + A2 * a));
                        pk1[j] = (bf16)(A0 + c * (A1 + A2 * c));
                    }
                } else {
                    #pragma unroll
                    for (int j = 0; j < 8; ++j) { pk0[j] = (bf16)0.0f; pk1[j] = (bf16)0.0f; }
                }
                *(bf16x8*)(rowp + (2 * xh + 1) * 8) = pk0;
                *(bf16x8*)(rowp + (2 * xh + 2) * 8) = pk1;
            } else {
                bf16x8 z;
                #pragma unroll
                for (int j = 0; j < 8; ++j) z[j] = (bf16)0.0f;
                *(bf16x8*)(rowp + 0) = z;            // xp=0   (xi=-1, conv pad)
                *(bf16x8*)(rowp + 129 * 8) = z;      // xp=129 (xi=128, conv pad)
            }
        }
    };

    // Weight DMA, chunk c: 24 units of 1 KB -> EXACTLY 3 loads per wave, uniform.
    auto wdma = [&](int c) {
        #pragma unroll
        for (int k2 = 0; k2 < 3; ++k2) {
            const int u = wv + (k2 << 3);
            const bf16* g = wrb + c * 12288 + u * 512 + lane * 8;
            __builtin_amdgcn_global_load_lds(
                (const __attribute__((address_space(1))) void*)g,
                (__attribute__((address_space(3))) void*)(wlds + u * 512),
                16, 0, 0);
        }
    };

    f32x16 acc[2];
    #pragma unroll
    for (int k = 0; k < 16; ++k) { acc[0][k] = 0.0f; acc[1][k] = 0.0f; }

    float2 v[16];

    // ---- Prologue: stage chunk 0, start weights(0) + stage(1). ----
    sload(0, v);
    spack(0, v);                       // compiler inserts vmcnt before v use
    wdma(0);                           // Q: w0(3)
    sload(1, v);                       // Q: w0(3), s1(16)
    asm volatile("s_waitcnt lgkmcnt(0)" ::: "memory");
    asm volatile("s_waitcnt vmcnt(16)" ::: "memory");   // w0 landed; s1 flying
    __builtin_amdgcn_sched_barrier(0);
    __builtin_amdgcn_s_barrier();      // stag0 + wlds0 visible to all
    __builtin_amdgcn_sched_barrier(0);

    const bf16x8* wptr = (const bf16x8*)wlds;

    for (int k = 0; k < 4; ++k) {
        // MFMA(k): LDS-only (A from wlds, B from stag[k&1]); s(k+1) in flight.
        const bf16x8* ifr = (const bf16x8*)stag[k & 1];
        __builtin_amdgcn_s_setprio(1);
        #pragma unroll
        for (int ky = 0; ky < 3; ++ky) {
            const int r = yl + ky;
            #pragma unroll
            for (int kx = 0; kx < 3; ++kx) {
                const int slice = ky * 3 + kx;
                bf16x8 a0 = wptr[(slice * 2 + half) * 64 + lm];
                bf16x8 a1 = wptr[(slice * 2 + half) * 64 + 32 + lm];
                bf16x8 b0 = ifr[(r * 2 + half) * 130 + Xh + lm + kx];   // conflict-free b128
                acc[0] = __builtin_amdgcn_mfma_f32_32x32x16_bf16(a0, b0, acc[0], 0, 0, 0);
                acc[1] = __builtin_amdgcn_mfma_f32_32x32x16_bf16(a1, b0, acc[1], 0, 0, 0);
            }
        }
        __builtin_amdgcn_s_setprio(0);
        if (k < 3) {
            __builtin_amdgcn_sched_barrier(0);
            __builtin_amdgcn_s_barrier();        // all waves done reading wlds(k)/stag
            __builtin_amdgcn_sched_barrier(0);
            wdma(k + 1);                         // Q: s(k+1)16, w(k+1)3
            spack((k + 1) & 1, v);               // compiler vmcnt(3) retires s(k+1)
            if (k < 2) sload(k + 2, v);          // Q: w(k+1)3, s(k+2)16
            asm volatile("s_waitcnt lgkmcnt(0)" ::: "memory");
            if (k < 2) asm volatile("s_waitcnt vmcnt(16)" ::: "memory");  // w landed, s flying
            else       asm volatile("s_waitcnt vmcnt(0)"  ::: "memory");
            __builtin_amdgcn_sched_barrier(0);
            __builtin_amdgcn_s_barrier();        // stag(k+1) + wlds(k+1) visible
            __builtin_amdgcn_sched_barrier(0);
        }
    }

    // ---- Epilogue: direct stores. Half-wave = 32 lanes x 4 B = one full
    // 128-B line per (o,y) segment; every output line written exactly once. ----
    // C/D layout: col = lane&31 (x), row-in-32 = (rg&3) + 8*(rg>>2) + 4*half (o).
    const int ybase = (n * OO * HH + (y0 + yl)) * WW;
    #pragma unroll
    for (int p = 0; p < 2; ++p)
        #pragma unroll
        for (int rg = 0; rg < 16; ++rg) {
            const int o = (rg & 3) + 8 * (rg >> 2) + 4 * half + 32 * p;
            out[ybase + o * (HH * WW) + Xh + lm] = acc[p][rg];
        }
}

extern "C" void kernel_launch(void* const* d_in, const int* in_sizes, int n_in,
                              void* d_out, int out_size, void* d_ws, size_t ws_size,
                              hipStream_t stream) {
    const float* img = (const float*)d_in[0];
    const float* w   = (const float*)d_in[1];
    // d_in[2] (identity_kernel) unused: its branch convolves exact zeros.
    float* out = (float*)d_out;
    bf16* wrb  = (bf16*)d_ws;    // 49152 bf16 = 98304 B repacked+padded weights

    repack_w<<<192, 256, 0, stream>>>(w, wrb);
    conv_mfma<<<NN * (HH / 2), 512, 0, stream>>>(img, wrb, out);
}